// Round 1
// baseline (999.317 us; speedup 1.0000x reference)
//
#include <hip/hip_runtime.h>
#include <math.h>

#ifndef M_PI
#define M_PI 3.14159265358979323846
#endif

#define HP   2080          // padded height (2048 + 2*16)
#define WP   2080          // padded width
#define MARG 16
#define HOUT 2048
#define WOUT 2048
#define RAD  26            // truncation radius; g[26]/g[0] ~ 4e-16
#define SEG  256           // horizontal pass segment width

// --- exact discrete filter taps: g[n] = (1/N) sum_j exp(-f_j^2 * 200) cos(2*pi*j*n/N)
__global__ void weights_kernel(float* __restrict__ w) {
    int n = threadIdx.x;
    if (n > RAD) return;
    const double N = (double)WP;
    double s = 0.0;
    for (int j = 0; j < WP; ++j) {
        double f = ((j <= WP / 2) ? (double)j : (double)(j - WP)) / N;
        double G = exp(-(f * f) * 200.0);   // 1/(2*0.05^2) = 200
        s += G * cos(2.0 * M_PI * (double)j * (double)n / N);
    }
    w[n] = (float)(s / N);
}

// --- bilinear scatter-add splat (matches reference clip/mod semantics)
__global__ void splat_kernel(const float2* __restrict__ pos,
                             const float* __restrict__ inten,
                             float* __restrict__ canvas, int n) {
    int i = blockIdx.x * blockDim.x + threadIdx.x;
    if (i >= n) return;
    float2 p = pos[i];
    float I  = inten[i];
    float px = p.x + (float)MARG;
    float py = p.y + (float)MARG;
    int col = (int)floorf(px);
    int row = (int)floorf(py);
    row = min(max(row, 0), HP - 1);
    col = min(max(col, 0), WP - 1);
    float dy = py - (float)row;
    float dx = px - (float)col;
    int row1 = (row + 1 == HP) ? 0 : row + 1;
    int col1 = (col + 1 == WP) ? 0 : col + 1;
    float omdy = 1.0f - dy, omdx = 1.0f - dx;
    atomicAdd(&canvas[row  * WP + col ], omdy * omdx * I);
    atomicAdd(&canvas[row1 * WP + col ], dy   * omdx * I);
    atomicAdd(&canvas[row  * WP + col1], omdy * dx   * I);
    atomicAdd(&canvas[row1 * WP + col1], dy   * dx   * I);
}

// --- horizontal convolution: temp[y][x] = sum_t w[|t|] * canvas[y][x+t]
__global__ void hconv_kernel(const float* __restrict__ canvas,
                             float* __restrict__ temp,
                             const float* __restrict__ w) {
    __shared__ float s[SEG + 2 * RAD];
    __shared__ float wl[RAD + 1];
    const int y   = blockIdx.y;
    const int x0  = blockIdx.x * SEG;
    const int tid = threadIdx.x;
    if (tid <= RAD) wl[tid] = w[tid];
    for (int i = tid; i < SEG + 2 * RAD; i += SEG) {
        int x = x0 + i - RAD;
        s[i] = (x >= 0 && x < WP) ? canvas[y * WP + x] : 0.0f;
    }
    __syncthreads();
    int x = x0 + tid;
    if (x < WP) {
        float acc = s[tid + RAD] * wl[0];
#pragma unroll
        for (int t = 1; t <= RAD; ++t)
            acc += (s[tid + RAD - t] + s[tid + RAD + t]) * wl[t];
        temp[y * WP + x] = acc;
    }
}

// --- vertical convolution + crop: out[oy][ox] = sum_t w[|t|] * temp[oy+16+t][ox+16]
#define TW 64
#define TH 64
__global__ void vconv_kernel(const float* __restrict__ temp,
                             float* __restrict__ out,
                             const float* __restrict__ w) {
    __shared__ float s[TH + 2 * RAD][TW];   // 116 x 64 floats = 29.7 KB
    __shared__ float wl[RAD + 1];
    const int lx  = threadIdx.x;            // 0..63
    const int ly  = threadIdx.y;            // 0..3
    const int tid = ly * TW + lx;
    if (tid <= RAD) wl[tid] = w[tid];
    const int ox0 = blockIdx.x * TW;
    const int oy0 = blockIdx.y * TH;
    const int cx  = ox0 + lx + MARG;        // canvas column (< 2080 always)
    for (int r = ly; r < TH + 2 * RAD; r += 4) {
        int cy = oy0 + MARG - RAD + r;
        s[r][lx] = (cy >= 0 && cy < HP) ? temp[cy * WP + cx] : 0.0f;
    }
    __syncthreads();
    for (int yy = ly; yy < TH; yy += 4) {
        float acc = s[yy + RAD][lx] * wl[0];
#pragma unroll
        for (int t = 1; t <= RAD; ++t)
            acc += (s[yy + RAD - t][lx] + s[yy + RAD + t][lx]) * wl[t];
        out[(oy0 + yy) * WOUT + ox0 + lx] = acc;
    }
}

extern "C" void kernel_launch(void* const* d_in, const int* in_sizes, int n_in,
                              void* d_out, int out_size, void* d_ws, size_t ws_size,
                              hipStream_t stream) {
    const float2* pos   = (const float2*)d_in[0];   // (N,2) as (x,y)
    const float*  inten = (const float*)d_in[1];
    const int n = in_sizes[1];

    float* canvas = (float*)d_ws;                   // HP*WP floats
    float* temp   = canvas + (size_t)HP * WP;       // HP*WP floats
    float* w      = temp + (size_t)HP * WP;         // RAD+1 floats

    hipMemsetAsync(canvas, 0, (size_t)HP * WP * sizeof(float), stream);
    weights_kernel<<<1, 64, 0, stream>>>(w);
    splat_kernel<<<(n + 255) / 256, 256, 0, stream>>>(pos, inten, canvas, n);
    hconv_kernel<<<dim3((WP + SEG - 1) / SEG, HP), SEG, 0, stream>>>(canvas, temp, w);
    vconv_kernel<<<dim3(WOUT / TW, HOUT / TH), dim3(TW, 4), 0, stream>>>(temp, (float*)d_out, w);
}

// Round 2
// 326.473 us; speedup vs baseline: 3.0610x; 3.0610x over previous
//
#include <hip/hip_runtime.h>
#include <math.h>

#ifndef M_PI
#define M_PI 3.14159265358979323846
#endif

#define HP   2080          // padded height (2048 + 2*16)
#define WP   2080          // padded width
#define MARG 16
#define HOUT 2048
#define WOUT 2048
#define RAD  26            // truncation radius; g[26]/g[0] ~ 4e-16
#define SEG  256           // horizontal pass segment width

// --- exact discrete filter taps: g[n] = (1/N) sum_j exp(-f_j^2 * 200) cos(2*pi*j*n/N)
// Parallelized: one block per tap n, 256 threads strided over j, LDS tree-reduce.
// (Previous version: 1 block x 64 threads, serial 2080-term f64 loop -> 787 us.)
__global__ void weights_kernel(float* __restrict__ w) {
    __shared__ double partial[256];
    const int n   = blockIdx.x;       // 0..RAD
    const int tid = threadIdx.x;
    const double N = (double)WP;
    double s = 0.0;
    for (int j = tid; j < WP; j += 256) {
        double f = ((j <= WP / 2) ? (double)j : (double)(j - WP)) / N;
        s += exp(-(f * f) * 200.0) * cos(2.0 * M_PI * (double)j * (double)n / N);
    }
    partial[tid] = s;
    __syncthreads();
    for (int off = 128; off > 0; off >>= 1) {
        if (tid < off) partial[tid] += partial[tid + off];
        __syncthreads();
    }
    if (tid == 0) w[n] = (float)(partial[0] / N);
}

// --- bilinear scatter-add splat (matches reference clip/mod semantics)
__global__ void splat_kernel(const float2* __restrict__ pos,
                             const float* __restrict__ inten,
                             float* __restrict__ canvas, int n) {
    int i = blockIdx.x * blockDim.x + threadIdx.x;
    if (i >= n) return;
    float2 p = pos[i];
    float I  = inten[i];
    float px = p.x + (float)MARG;
    float py = p.y + (float)MARG;
    int col = (int)floorf(px);
    int row = (int)floorf(py);
    row = min(max(row, 0), HP - 1);
    col = min(max(col, 0), WP - 1);
    float dy = py - (float)row;
    float dx = px - (float)col;
    int row1 = (row + 1 == HP) ? 0 : row + 1;
    int col1 = (col + 1 == WP) ? 0 : col + 1;
    float omdy = 1.0f - dy, omdx = 1.0f - dx;
    atomicAdd(&canvas[row  * WP + col ], omdy * omdx * I);
    atomicAdd(&canvas[row1 * WP + col ], dy   * omdx * I);
    atomicAdd(&canvas[row  * WP + col1], omdy * dx   * I);
    atomicAdd(&canvas[row1 * WP + col1], dy   * dx   * I);
}

// --- horizontal convolution: temp[y][x] = sum_t w[|t|] * canvas[y][x+t]
__global__ void hconv_kernel(const float* __restrict__ canvas,
                             float* __restrict__ temp,
                             const float* __restrict__ w) {
    __shared__ float s[SEG + 2 * RAD];
    __shared__ float wl[RAD + 1];
    const int y   = blockIdx.y;
    const int x0  = blockIdx.x * SEG;
    const int tid = threadIdx.x;
    if (tid <= RAD) wl[tid] = w[tid];
    for (int i = tid; i < SEG + 2 * RAD; i += SEG) {
        int x = x0 + i - RAD;
        s[i] = (x >= 0 && x < WP) ? canvas[y * WP + x] : 0.0f;
    }
    __syncthreads();
    int x = x0 + tid;
    if (x < WP) {
        float acc = s[tid + RAD] * wl[0];
#pragma unroll
        for (int t = 1; t <= RAD; ++t)
            acc += (s[tid + RAD - t] + s[tid + RAD + t]) * wl[t];
        temp[y * WP + x] = acc;
    }
}

// --- vertical convolution + crop: out[oy][ox] = sum_t w[|t|] * temp[oy+16+t][ox+16]
#define TW 64
#define TH 64
__global__ void vconv_kernel(const float* __restrict__ temp,
                             float* __restrict__ out,
                             const float* __restrict__ w) {
    __shared__ float s[TH + 2 * RAD][TW];   // 116 x 64 floats = 29.7 KB
    __shared__ float wl[RAD + 1];
    const int lx  = threadIdx.x;            // 0..63
    const int ly  = threadIdx.y;            // 0..3
    const int tid = ly * TW + lx;
    if (tid <= RAD) wl[tid] = w[tid];
    const int ox0 = blockIdx.x * TW;
    const int oy0 = blockIdx.y * TH;
    const int cx  = ox0 + lx + MARG;        // canvas column (< 2080 always)
    for (int r = ly; r < TH + 2 * RAD; r += 4) {
        int cy = oy0 + MARG - RAD + r;
        s[r][lx] = (cy >= 0 && cy < HP) ? temp[cy * WP + cx] : 0.0f;
    }
    __syncthreads();
    for (int yy = ly; yy < TH; yy += 4) {
        float acc = s[yy + RAD][lx] * wl[0];
#pragma unroll
        for (int t = 1; t <= RAD; ++t)
            acc += (s[yy + RAD - t][lx] + s[yy + RAD + t][lx]) * wl[t];
        out[(oy0 + yy) * WOUT + ox0 + lx] = acc;
    }
}

extern "C" void kernel_launch(void* const* d_in, const int* in_sizes, int n_in,
                              void* d_out, int out_size, void* d_ws, size_t ws_size,
                              hipStream_t stream) {
    const float2* pos   = (const float2*)d_in[0];   // (N,2) as (x,y)
    const float*  inten = (const float*)d_in[1];
    const int n = in_sizes[1];

    float* canvas = (float*)d_ws;                   // HP*WP floats
    float* temp   = canvas + (size_t)HP * WP;       // HP*WP floats
    float* w      = temp + (size_t)HP * WP;         // RAD+1 floats

    hipMemsetAsync(canvas, 0, (size_t)HP * WP * sizeof(float), stream);
    weights_kernel<<<RAD + 1, 256, 0, stream>>>(w);
    splat_kernel<<<(n + 255) / 256, 256, 0, stream>>>(pos, inten, canvas, n);
    hconv_kernel<<<dim3((WP + SEG - 1) / SEG, HP), SEG, 0, stream>>>(canvas, temp, w);
    vconv_kernel<<<dim3(WOUT / TW, HOUT / TH), dim3(TW, 4), 0, stream>>>(temp, (float*)d_out, w);
}

// Round 3
// 228.951 us; speedup vs baseline: 4.3648x; 1.4260x over previous
//
#include <hip/hip_runtime.h>
#include <math.h>

#ifndef M_PI
#define M_PI 3.14159265358979323846
#endif

#define HP   2080          // padded height (2048 + 2*16)
#define WP   2080          // padded width
#define MARG 16
#define HOUT 2048
#define WOUT 2048
#define RAD  26            // truncation radius; g[26]/g[0] ~ 4e-16
#define SEG  256           // horizontal pass segment width
#define TDIM 17            // 17x17 tiles of 128x128 cover 2080^2
#define NT   (TDIM * TDIM) // 289 tiles
#define TS   128           // tile size
#define TP   129           // tile + halo

__device__ __forceinline__ int bin_of(float px, float py) {
    int col = (int)floorf(px), row = (int)floorf(py);
    row = min(max(row, 0), HP - 1);
    col = min(max(col, 0), WP - 1);
    return (row >> 7) * TDIM + (col >> 7);
}

// --- exact discrete filter taps: g[n] = (1/N) sum_j exp(-f_j^2 * 200) cos(2*pi*j*n/N)
__global__ void weights_kernel(float* __restrict__ w) {
    __shared__ double partial[256];
    const int n   = blockIdx.x;       // 0..RAD
    const int tid = threadIdx.x;
    const double N = (double)WP;
    double s = 0.0;
    for (int j = tid; j < WP; j += 256) {
        double f = ((j <= WP / 2) ? (double)j : (double)(j - WP)) / N;
        s += exp(-(f * f) * 200.0) * cos(2.0 * M_PI * (double)j * (double)n / N);
    }
    partial[tid] = s;
    __syncthreads();
    for (int off = 128; off > 0; off >>= 1) {
        if (tid < off) partial[tid] += partial[tid + off];
        __syncthreads();
    }
    if (tid == 0) w[n] = (float)(partial[0] / N);
}

// --- pass 1: per-tile histogram (LDS-aggregated)
__global__ void hist_kernel(const float2* __restrict__ pos, int* __restrict__ hist, int n) {
    __shared__ int lh[NT];
    for (int i = threadIdx.x; i < NT; i += blockDim.x) lh[i] = 0;
    __syncthreads();
    for (int i = blockIdx.x * blockDim.x + threadIdx.x; i < n; i += gridDim.x * blockDim.x) {
        float2 p = pos[i];
        atomicAdd(&lh[bin_of(p.x + MARG, p.y + MARG)], 1);
    }
    __syncthreads();
    for (int i = threadIdx.x; i < NT; i += blockDim.x)
        if (lh[i]) atomicAdd(&hist[i], lh[i]);
}

// --- pass 2: exclusive scan of 289 bins (single block, Hillis-Steele)
__global__ void scan_kernel(const int* __restrict__ hist,
                            int* __restrict__ binStart, int* __restrict__ cursor) {
    __shared__ int a[512], b[512];
    const int tid = threadIdx.x;
    a[tid] = (tid < NT) ? hist[tid] : 0;
    __syncthreads();
    int* src = a; int* dst = b;
    for (int off = 1; off < 512; off <<= 1) {
        dst[tid] = src[tid] + ((tid >= off) ? src[tid - off] : 0);
        __syncthreads();
        int* t = src; src = dst; dst = t;
    }
    // src = inclusive scan
    if (tid < NT) {
        int excl = src[tid] - ((tid < NT) ? hist[tid] : 0);
        binStart[tid] = excl;
        cursor[tid]   = excl;
    }
    if (tid == 0) binStart[NT] = src[NT - 1];
}

// --- pass 3: scatter points into bins (per-block reservation, LDS local cursors)
__global__ void scatter_kernel(const float2* __restrict__ pos,
                               const float* __restrict__ inten,
                               int* __restrict__ cursor,
                               float4* __restrict__ bins, int n) {
    __shared__ int lhist[NT];
    __shared__ int lbase[NT];
    const int tid = threadIdx.x;
    for (int i = tid; i < NT; i += blockDim.x) lhist[i] = 0;
    __syncthreads();
    const int stride = gridDim.x * blockDim.x;
    const int start  = blockIdx.x * blockDim.x + tid;
    for (int i = start; i < n; i += stride) {
        float2 p = pos[i];
        atomicAdd(&lhist[bin_of(p.x + MARG, p.y + MARG)], 1);
    }
    __syncthreads();
    for (int i = tid; i < NT; i += blockDim.x) {
        int c = lhist[i];
        lbase[i] = (c > 0) ? atomicAdd(&cursor[i], c) : 0;
        lhist[i] = 0;
    }
    __syncthreads();
    for (int i = start; i < n; i += stride) {
        float2 p = pos[i];
        float px = p.x + MARG, py = p.y + MARG;
        int bin = bin_of(px, py);
        int off = atomicAdd(&lhist[bin], 1);
        bins[lbase[bin] + off] = make_float4(px, py, inten[i], 0.0f);
    }
}

// --- pass 4: per-tile splat via LDS atomics, then coalesced canvas write
__global__ __launch_bounds__(256) void tile_splat_kernel(const float4* __restrict__ bins,
                                                         const int* __restrict__ binStart,
                                                         float* __restrict__ canvas) {
    __shared__ float tile[TP * TP];   // 129*129*4 = 66.6 KB
    const int b  = blockIdx.x;
    const int ti = b / TDIM, tj = b % TDIM;
    for (int i = threadIdx.x; i < TP * TP; i += 256) tile[i] = 0.0f;
    __syncthreads();
    const int s0 = binStart[b], s1 = binStart[b + 1];
    for (int i = s0 + threadIdx.x; i < s1; i += 256) {
        float4 r = bins[i];
        float px = r.x, py = r.y, I = r.z;
        int col = (int)floorf(px), row = (int)floorf(py);
        row = min(max(row, 0), HP - 1);
        col = min(max(col, 0), WP - 1);
        float dy = py - (float)row, dx = px - (float)col;
        int lr = row - ti * TS, lc = col - tj * TS;   // in [0,127] by binning
        float omdy = 1.0f - dy, omdx = 1.0f - dx;
        atomicAdd(&tile[lr * TP + lc],           omdy * omdx * I);
        atomicAdd(&tile[(lr + 1) * TP + lc],     dy   * omdx * I);
        atomicAdd(&tile[lr * TP + lc + 1],       omdy * dx   * I);
        atomicAdd(&tile[(lr + 1) * TP + lc + 1], dy   * dx   * I);
    }
    __syncthreads();
    for (int i = threadIdx.x; i < TP * TP; i += 256) {
        int r = i / TP, c = i - r * TP;
        int gr = ti * TS + r, gc = tj * TS + c;
        if (gr < HP && gc < WP) {
            float v = tile[i];
            bool edge = (r == 0) | (c == 0) | (r == TS) | (c == TS);
            if (edge) { if (v != 0.0f) atomicAdd(&canvas[gr * WP + gc], v); }
            else canvas[gr * WP + gc] = v;   // interior (1..127)^2 is tile-exclusive
        }
    }
}

// --- horizontal convolution: temp[y][x] = sum_t w[|t|] * canvas[y][x+t]
__global__ void hconv_kernel(const float* __restrict__ canvas,
                             float* __restrict__ temp,
                             const float* __restrict__ w) {
    __shared__ float s[SEG + 2 * RAD];
    __shared__ float wl[RAD + 1];
    const int y   = blockIdx.y;
    const int x0  = blockIdx.x * SEG;
    const int tid = threadIdx.x;
    if (tid <= RAD) wl[tid] = w[tid];
    for (int i = tid; i < SEG + 2 * RAD; i += SEG) {
        int x = x0 + i - RAD;
        s[i] = (x >= 0 && x < WP) ? canvas[y * WP + x] : 0.0f;
    }
    __syncthreads();
    int x = x0 + tid;
    if (x < WP) {
        float acc = s[tid + RAD] * wl[0];
#pragma unroll
        for (int t = 1; t <= RAD; ++t)
            acc += (s[tid + RAD - t] + s[tid + RAD + t]) * wl[t];
        temp[y * WP + x] = acc;
    }
}

// --- vertical convolution + crop
#define TW 64
#define TH 64
__global__ void vconv_kernel(const float* __restrict__ temp,
                             float* __restrict__ out,
                             const float* __restrict__ w) {
    __shared__ float s[TH + 2 * RAD][TW];
    __shared__ float wl[RAD + 1];
    const int lx  = threadIdx.x;
    const int ly  = threadIdx.y;
    const int tid = ly * TW + lx;
    if (tid <= RAD) wl[tid] = w[tid];
    const int ox0 = blockIdx.x * TW;
    const int oy0 = blockIdx.y * TH;
    const int cx  = ox0 + lx + MARG;
    for (int r = ly; r < TH + 2 * RAD; r += 4) {
        int cy = oy0 + MARG - RAD + r;
        s[r][lx] = (cy >= 0 && cy < HP) ? temp[cy * WP + cx] : 0.0f;
    }
    __syncthreads();
    for (int yy = ly; yy < TH; yy += 4) {
        float acc = s[yy + RAD][lx] * wl[0];
#pragma unroll
        for (int t = 1; t <= RAD; ++t)
            acc += (s[yy + RAD - t][lx] + s[yy + RAD + t][lx]) * wl[t];
        out[(oy0 + yy) * WOUT + ox0 + lx] = acc;
    }
}

extern "C" void kernel_launch(void* const* d_in, const int* in_sizes, int n_in,
                              void* d_out, int out_size, void* d_ws, size_t ws_size,
                              hipStream_t stream) {
    const float2* pos   = (const float2*)d_in[0];   // (N,2) as (x,y)
    const float*  inten = (const float*)d_in[1];
    const int n = in_sizes[1];

    float*  canvas = (float*)d_ws;                          // HP*WP floats
    float*  temp   = canvas + (size_t)HP * WP;              // HP*WP floats
    float4* bins   = (float4*)temp;                         // n float4 (16 MB <= 17.3 MB), aliases temp
    int*    ints   = (int*)(temp + 4050000);                // past bins (n*4 = 4,000,000 floats)
    int*    hist     = ints;                                // NT
    int*    binStart = hist + NT;                           // NT+1
    int*    cursor   = binStart + NT + 1;                   // NT
    float*  w      = temp + (size_t)HP * WP;                // RAD+1 floats (outlives temp's bin use)

    hipMemsetAsync(canvas, 0, (size_t)HP * WP * sizeof(float), stream);
    hipMemsetAsync(hist, 0, NT * sizeof(int), stream);
    weights_kernel<<<RAD + 1, 256, 0, stream>>>(w);
    hist_kernel<<<512, 256, 0, stream>>>(pos, hist, n);
    scan_kernel<<<1, 512, 0, stream>>>(hist, binStart, cursor);
    scatter_kernel<<<512, 256, 0, stream>>>(pos, inten, cursor, bins, n);
    tile_splat_kernel<<<NT, 256, 0, stream>>>(bins, binStart, canvas);
    hconv_kernel<<<dim3((WP + SEG - 1) / SEG, HP), SEG, 0, stream>>>(canvas, temp, w);
    vconv_kernel<<<dim3(WOUT / TW, HOUT / TH), dim3(TW, 4), 0, stream>>>(temp, (float*)d_out, w);
}

// Round 4
// 203.455 us; speedup vs baseline: 4.9117x; 1.1253x over previous
//
#include <hip/hip_runtime.h>
#include <math.h>

#ifndef M_PI
#define M_PI 3.14159265358979323846
#endif

#define HP   2080          // padded height (2048 + 2*16)
#define WP   2080          // padded width
#define MARG 16
#define HOUT 2048
#define WOUT 2048
#define RAD  26            // truncation radius; g[26]/g[0] ~ 4e-16
#define SEG  256           // horizontal pass segment width
#define TSH  6             // log2(tile size)
#define TS   64            // splat tile size
#define TP   65            // tile + halo (16.9 KB LDS -> 4 blocks/CU, 32 waves/CU)
#define TDIM 33            // ceil(2080/64)
#define NT   (TDIM * TDIM) // 1089 bins

__device__ __forceinline__ int bin_of(float px, float py) {
    int col = (int)floorf(px), row = (int)floorf(py);
    row = min(max(row, 0), HP - 1);
    col = min(max(col, 0), WP - 1);
    return (row >> TSH) * TDIM + (col >> TSH);
}

// --- exact discrete filter taps: g[n] = (1/N) sum_j exp(-f_j^2 * 200) cos(2*pi*j*n/N)
__global__ void weights_kernel(float* __restrict__ w) {
    __shared__ double partial[256];
    const int n   = blockIdx.x;       // 0..RAD
    const int tid = threadIdx.x;
    const double N = (double)WP;
    double s = 0.0;
    for (int j = tid; j < WP; j += 256) {
        double f = ((j <= WP / 2) ? (double)j : (double)(j - WP)) / N;
        s += exp(-(f * f) * 200.0) * cos(2.0 * M_PI * (double)j * (double)n / N);
    }
    partial[tid] = s;
    __syncthreads();
    for (int off = 128; off > 0; off >>= 1) {
        if (tid < off) partial[tid] += partial[tid + off];
        __syncthreads();
    }
    if (tid == 0) w[n] = (float)(partial[0] / N);
}

// --- pass 1: per-bin histogram (LDS-aggregated)
__global__ void hist_kernel(const float2* __restrict__ pos, int* __restrict__ hist, int n) {
    __shared__ int lh[NT];
    for (int i = threadIdx.x; i < NT; i += blockDim.x) lh[i] = 0;
    __syncthreads();
    for (int i = blockIdx.x * blockDim.x + threadIdx.x; i < n; i += gridDim.x * blockDim.x) {
        float2 p = pos[i];
        atomicAdd(&lh[bin_of(p.x + MARG, p.y + MARG)], 1);
    }
    __syncthreads();
    for (int i = threadIdx.x; i < NT; i += blockDim.x)
        if (lh[i]) atomicAdd(&hist[i], lh[i]);
}

// --- pass 2: exclusive scan of NT=1089 bins (1 block x 256 thr, 5 elems/thread)
__global__ void scan_kernel(const int* __restrict__ hist,
                            int* __restrict__ binStart, int* __restrict__ cursor) {
    __shared__ int a[256], b[256];
    const int tid = threadIdx.x;
    int v[5]; int s = 0;
#pragma unroll
    for (int k = 0; k < 5; ++k) {
        int idx = tid * 5 + k;
        int h = (idx < NT) ? hist[idx] : 0;
        v[k] = h; s += h;
    }
    a[tid] = s;
    __syncthreads();
    int* src = a; int* dst = b;
    for (int off = 1; off < 256; off <<= 1) {
        dst[tid] = src[tid] + ((tid >= off) ? src[tid - off] : 0);
        __syncthreads();
        int* t = src; src = dst; dst = t;
    }
    int run = src[tid] - s;   // exclusive prefix of this thread's chunk
#pragma unroll
    for (int k = 0; k < 5; ++k) {
        int idx = tid * 5 + k;
        if (idx <= NT) {
            binStart[idx] = run;
            if (idx < NT) cursor[idx] = run;
        }
        run += v[k];
    }
}

// --- pass 3: scatter points into bins (per-block reservation, LDS local cursors)
//     256 blocks x 512 thr: ~3.6 float4 per (block,bin) -> ~57 B runs (L2 granule)
__global__ void scatter_kernel(const float2* __restrict__ pos,
                               const float* __restrict__ inten,
                               int* __restrict__ cursor,
                               float4* __restrict__ bins, int n) {
    __shared__ int lhist[NT];
    __shared__ int lbase[NT];
    const int tid = threadIdx.x;
    for (int i = tid; i < NT; i += blockDim.x) lhist[i] = 0;
    __syncthreads();
    const int stride = gridDim.x * blockDim.x;
    const int start  = blockIdx.x * blockDim.x + tid;
    for (int i = start; i < n; i += stride) {
        float2 p = pos[i];
        atomicAdd(&lhist[bin_of(p.x + MARG, p.y + MARG)], 1);
    }
    __syncthreads();
    for (int i = tid; i < NT; i += blockDim.x) {
        int c = lhist[i];
        lbase[i] = (c > 0) ? atomicAdd(&cursor[i], c) : 0;
        lhist[i] = 0;
    }
    __syncthreads();
    for (int i = start; i < n; i += stride) {
        float2 p = pos[i];
        float px = p.x + MARG, py = p.y + MARG;
        int bin = bin_of(px, py);
        int off = atomicAdd(&lhist[bin], 1);
        bins[lbase[bin] + off] = make_float4(px, py, inten[i], 0.0f);
    }
}

// --- pass 4: per-tile splat via LDS atomics, then coalesced canvas write
__global__ __launch_bounds__(512, 8) void tile_splat_kernel(const float4* __restrict__ bins,
                                                            const int* __restrict__ binStart,
                                                            float* __restrict__ canvas) {
    __shared__ float tile[TP * TP];   // 65*65*4 = 16.9 KB
    const int b  = blockIdx.x;
    const int ti = b / TDIM, tj = b % TDIM;
    for (int i = threadIdx.x; i < TP * TP; i += 512) tile[i] = 0.0f;
    __syncthreads();
    const int s0 = binStart[b], s1 = binStart[b + 1];
    for (int i = s0 + threadIdx.x; i < s1; i += 512) {
        float4 r = bins[i];
        float px = r.x, py = r.y, I = r.z;
        int col = (int)floorf(px), row = (int)floorf(py);
        row = min(max(row, 0), HP - 1);
        col = min(max(col, 0), WP - 1);
        float dy = py - (float)row, dx = px - (float)col;
        int lr = row - (ti << TSH), lc = col - (tj << TSH);   // in [0,63] by binning
        float omdy = 1.0f - dy, omdx = 1.0f - dx;
        atomicAdd(&tile[lr * TP + lc],           omdy * omdx * I);
        atomicAdd(&tile[(lr + 1) * TP + lc],     dy   * omdx * I);
        atomicAdd(&tile[lr * TP + lc + 1],       omdy * dx   * I);
        atomicAdd(&tile[(lr + 1) * TP + lc + 1], dy   * dx   * I);
    }
    __syncthreads();
    for (int i = threadIdx.x; i < TP * TP; i += 512) {
        int r = i / TP, c = i - r * TP;
        int gr = (ti << TSH) + r, gc = (tj << TSH) + c;
        if (gr < HP && gc < WP) {
            float v = tile[i];
            bool edge = (r == 0) | (c == 0) | (r == TS) | (c == TS);
            if (edge) { if (v != 0.0f) atomicAdd(&canvas[gr * WP + gc], v); }
            else canvas[gr * WP + gc] = v;   // interior (1..63)^2 is tile-exclusive
        }
    }
}

// --- horizontal convolution: temp[y][x] = sum_t w[|t|] * canvas[y][x+t]
__global__ void hconv_kernel(const float* __restrict__ canvas,
                             float* __restrict__ temp,
                             const float* __restrict__ w) {
    __shared__ float s[SEG + 2 * RAD];
    __shared__ float wl[RAD + 1];
    const int y   = blockIdx.y;
    const int x0  = blockIdx.x * SEG;
    const int tid = threadIdx.x;
    if (tid <= RAD) wl[tid] = w[tid];
    for (int i = tid; i < SEG + 2 * RAD; i += SEG) {
        int x = x0 + i - RAD;
        s[i] = (x >= 0 && x < WP) ? canvas[y * WP + x] : 0.0f;
    }
    __syncthreads();
    int x = x0 + tid;
    if (x < WP) {
        float acc = s[tid + RAD] * wl[0];
#pragma unroll
        for (int t = 1; t <= RAD; ++t)
            acc += (s[tid + RAD - t] + s[tid + RAD + t]) * wl[t];
        temp[y * WP + x] = acc;
    }
}

// --- vertical convolution + crop
#define TW 64
#define TH 64
__global__ void vconv_kernel(const float* __restrict__ temp,
                             float* __restrict__ out,
                             const float* __restrict__ w) {
    __shared__ float s[TH + 2 * RAD][TW];
    __shared__ float wl[RAD + 1];
    const int lx  = threadIdx.x;
    const int ly  = threadIdx.y;
    const int tid = ly * TW + lx;
    if (tid <= RAD) wl[tid] = w[tid];
    const int ox0 = blockIdx.x * TW;
    const int oy0 = blockIdx.y * TH;
    const int cx  = ox0 + lx + MARG;
    for (int r = ly; r < TH + 2 * RAD; r += 4) {
        int cy = oy0 + MARG - RAD + r;
        s[r][lx] = (cy >= 0 && cy < HP) ? temp[cy * WP + cx] : 0.0f;
    }
    __syncthreads();
    for (int yy = ly; yy < TH; yy += 4) {
        float acc = s[yy + RAD][lx] * wl[0];
#pragma unroll
        for (int t = 1; t <= RAD; ++t)
            acc += (s[yy + RAD - t][lx] + s[yy + RAD + t][lx]) * wl[t];
        out[(oy0 + yy) * WOUT + ox0 + lx] = acc;
    }
}

extern "C" void kernel_launch(void* const* d_in, const int* in_sizes, int n_in,
                              void* d_out, int out_size, void* d_ws, size_t ws_size,
                              hipStream_t stream) {
    const float2* pos   = (const float2*)d_in[0];   // (N,2) as (x,y)
    const float*  inten = (const float*)d_in[1];
    const int n = in_sizes[1];

    float*  canvas = (float*)d_ws;                          // HP*WP floats
    float*  temp   = canvas + (size_t)HP * WP;              // HP*WP floats
    float4* bins   = (float4*)temp;                         // n float4 (16 MB), aliases temp
    int*    ints   = (int*)(temp + 4050000);                // past bins (n*4 = 4,000,000 floats)
    int*    hist     = ints;                                // NT
    int*    binStart = hist + NT;                           // NT+1
    int*    cursor   = binStart + NT + 1;                   // NT
    float*  w      = temp + (size_t)HP * WP;                // RAD+1 floats, after temp

    hipMemsetAsync(canvas, 0, (size_t)HP * WP * sizeof(float), stream);
    hipMemsetAsync(hist, 0, NT * sizeof(int), stream);
    weights_kernel<<<RAD + 1, 256, 0, stream>>>(w);
    hist_kernel<<<512, 256, 0, stream>>>(pos, hist, n);
    scan_kernel<<<1, 256, 0, stream>>>(hist, binStart, cursor);
    scatter_kernel<<<256, 512, 0, stream>>>(pos, inten, cursor, bins, n);
    tile_splat_kernel<<<NT, 512, 0, stream>>>(bins, binStart, canvas);
    hconv_kernel<<<dim3((WP + SEG - 1) / SEG, HP), SEG, 0, stream>>>(canvas, temp, w);
    vconv_kernel<<<dim3(WOUT / TW, HOUT / TH), dim3(TW, 4), 0, stream>>>(temp, (float*)d_out, w);
}